// Round 1
// baseline (652.336 us; speedup 1.0000x reference)
//
#include <hip/hip_runtime.h>
#include <cmath>

// ---------------------------------------------------------------------------
// EncoderLayer: x -> MHA -> +res -> LN1 -> FFN(GELU) -> +res -> LN2
// B=2 L=2048 D=1024 H=16 dk=64 F=4096  (M = B*L = 4096 rows)
// Internal compute: bf16 MFMA (16x16x32), fp32 accumulate, fp32 LN/residual.
// ---------------------------------------------------------------------------

typedef unsigned short u16;
typedef __attribute__((ext_vector_type(8))) __bf16 bf16x8;
typedef __attribute__((ext_vector_type(4))) float f32x4;

#define MFMA16(a, b, c) __builtin_amdgcn_mfma_f32_16x16x32_bf16(a, b, c, 0, 0, 0)

__device__ __forceinline__ u16 f2bf(float f) {
  unsigned int u = __builtin_bit_cast(unsigned int, f);
  u += 0x7fffu + ((u >> 16) & 1u);   // round-to-nearest-even
  return (u16)(u >> 16);
}

__device__ __forceinline__ bf16x8 ld_frag(const u16* p) {
  return __builtin_bit_cast(bf16x8, *(const uint4*)p);
}

// ---------------- fp32 -> bf16 elementwise convert (x) ----------------------
__global__ __launch_bounds__(256) void cvt_bf16_k(const float* __restrict__ src,
                                                  u16* __restrict__ dst) {
  int i = (blockIdx.x * 256 + threadIdx.x) * 4;
  float4 v = *(const float4*)(src + i);
  ushort4 o;
  o.x = f2bf(v.x); o.y = f2bf(v.y); o.z = f2bf(v.z); o.w = f2bf(v.w);
  *(ushort4*)(dst + i) = o;
}

// ---------------- fp32 [R][C] -> bf16 [C][R] transpose ----------------------
__global__ __launch_bounds__(256) void transpose_bf16_k(const float* __restrict__ src,
                                                        u16* __restrict__ dst,
                                                        int R, int C) {
  __shared__ float tile[32][33];
  int tx = threadIdx.x & 31, ty = threadIdx.x >> 5;  // 32 x 8
  int c0 = blockIdx.x * 32, r0 = blockIdx.y * 32;
#pragma unroll
  for (int i = 0; i < 4; i++)
    tile[ty + 8 * i][tx] = src[(long)(r0 + ty + 8 * i) * C + c0 + tx];
  __syncthreads();
#pragma unroll
  for (int i = 0; i < 4; i++)
    dst[(long)(c0 + ty + 8 * i) * R + r0 + tx] = f2bf(tile[tx][ty + 8 * i]);
}

// ---------------- GEMM: C[M][N] = A[M][K] * BT[N][K]^T ----------------------
// 64x64 block tile, 4 waves (each wave: 16 rows x 64 cols), BK=32.
// MODE 0: QKV epilogue (scatter to q [bh][L][dk] *0.125, k [bh][L][dk], vT [bh][dk][L])
// MODE 1: fp32 out + bias
// MODE 2: bf16 out + bias + exact GELU
template <int MODE>
__global__ __launch_bounds__(256) void gemm_k(
    const u16* __restrict__ A, const u16* __restrict__ BT, int M, int N, int K,
    const float* __restrict__ bias, float* __restrict__ outF, u16* __restrict__ outB,
    u16* __restrict__ qd, u16* __restrict__ kd, u16* __restrict__ vTd,
    const float* __restrict__ bq, const float* __restrict__ bk, const float* __restrict__ bv) {
  __shared__ u16 As[64][40];  // +8 pad: <=2-way bank aliasing (free)
  __shared__ u16 Bs[64][40];
  const int tid = threadIdx.x;
  const int wave = tid >> 6, lane = tid & 63, quad = lane >> 4, l16 = lane & 15;
  const int m0 = blockIdx.y * 64, n0 = blockIdx.x * 64;
  const int srow = tid >> 2, sseg = (tid & 3) * 8;
  const u16* aSrc = A + (long)(m0 + srow) * K + sseg;
  const u16* bSrc = BT + (long)(n0 + srow) * K + sseg;

  f32x4 acc[4] = {};
  for (int k0 = 0; k0 < K; k0 += 32) {
    __syncthreads();
    *(uint4*)&As[srow][sseg] = *(const uint4*)(aSrc + k0);
    *(uint4*)&Bs[srow][sseg] = *(const uint4*)(bSrc + k0);
    __syncthreads();
    bf16x8 a = ld_frag(&As[wave * 16 + l16][quad * 8]);
#pragma unroll
    for (int nt = 0; nt < 4; nt++) {
      bf16x8 b = ld_frag(&Bs[nt * 16 + l16][quad * 8]);
      acc[nt] = MFMA16(a, b, acc[nt]);
    }
  }

  if (MODE == 0) {
#pragma unroll
    for (int nt = 0; nt < 4; nt++) {
      int n = n0 + nt * 16 + l16;
      int mat = n >> 10, nn = n & 1023, hh = nn >> 6, dd = nn & 63;
      const float* bp = (mat == 0) ? bq : ((mat == 1) ? bk : bv);
      float bb = bp[nn];
#pragma unroll
      for (int r = 0; r < 4; r++) {
        int m = m0 + wave * 16 + quad * 4 + r;
        int bI = m >> 11, ll = m & 2047;
        float v = acc[nt][r] + bb;
        if (mat == 0) {
          qd[((long)((bI * 16 + hh) * 2048 + ll)) * 64 + dd] = f2bf(v * 0.125f);
        } else if (mat == 1) {
          kd[((long)((bI * 16 + hh) * 2048 + ll)) * 64 + dd] = f2bf(v);
        } else {
          vTd[((long)((bI * 16 + hh) * 64 + dd)) * 2048 + ll] = f2bf(v);
        }
      }
    }
  } else if (MODE == 1) {
#pragma unroll
    for (int nt = 0; nt < 4; nt++) {
      int n = n0 + nt * 16 + l16;
      float bb = bias[n];
#pragma unroll
      for (int r = 0; r < 4; r++) {
        int m = m0 + wave * 16 + quad * 4 + r;
        outF[(long)m * N + n] = acc[nt][r] + bb;
      }
    }
  } else {
#pragma unroll
    for (int nt = 0; nt < 4; nt++) {
      int n = n0 + nt * 16 + l16;
      float bb = bias[n];
#pragma unroll
      for (int r = 0; r < 4; r++) {
        int m = m0 + wave * 16 + quad * 4 + r;
        float v = acc[nt][r] + bb;
        v = 0.5f * v * (1.0f + erff(v * 0.70710678118654752f));  // exact GELU
        outB[(long)m * N + n] = f2bf(v);
      }
    }
  }
}

// ---------------- flash attention ------------------------------------------
// grid (L/64, B*H). 4 waves/block; wave handles 16 Q rows; 32-key chunks.
// q is pre-scaled by 1/sqrt(dk)=0.125. vT is [bh][dk][L] so PV B-frags are
// contiguous. P goes C-layout -> LDS -> A-layout (verified path).
__global__ __launch_bounds__(256) void attn_k(const u16* __restrict__ qd,
                                              const u16* __restrict__ kd,
                                              const u16* __restrict__ vTd,
                                              u16* __restrict__ ctx) {
  const int tid = threadIdx.x;
  const int wave = tid >> 6, lane = tid & 63, quad = lane >> 4, l16 = lane & 15;
  const int bh = blockIdx.y;
  const u16* Q = qd + (long)bh * 2048 * 64;
  const u16* Kp = kd + (long)bh * 2048 * 64;
  const u16* Vt = vTd + (long)bh * 64 * 2048;
  const int qbase = blockIdx.x * 64 + wave * 16;

  bf16x8 q0 = ld_frag(Q + (qbase + l16) * 64 + quad * 8);
  bf16x8 q1 = ld_frag(Q + (qbase + l16) * 64 + 32 + quad * 8);

  f32x4 o[4] = {};
  float mr[4] = {-__builtin_inff(), -__builtin_inff(), -__builtin_inff(), -__builtin_inff()};
  float lr[4] = {0.f, 0.f, 0.f, 0.f};

  __shared__ u16 P[4][16][40];

  for (int j0 = 0; j0 < 2048; j0 += 32) {
    bf16x8 k00 = ld_frag(Kp + (j0 + l16) * 64 + quad * 8);
    bf16x8 k01 = ld_frag(Kp + (j0 + l16) * 64 + 32 + quad * 8);
    bf16x8 k10 = ld_frag(Kp + (j0 + 16 + l16) * 64 + quad * 8);
    bf16x8 k11 = ld_frag(Kp + (j0 + 16 + l16) * 64 + 32 + quad * 8);
    f32x4 s0 = {}, s1 = {};
    s0 = MFMA16(q0, k00, s0);
    s0 = MFMA16(q1, k01, s0);
    s1 = MFMA16(q0, k10, s1);
    s1 = MFMA16(q1, k11, s1);

    float p0[4], p1[4];
#pragma unroll
    for (int r = 0; r < 4; r++) {
      float mx = fmaxf(s0[r], s1[r]);
      mx = fmaxf(mx, __shfl_xor(mx, 1));
      mx = fmaxf(mx, __shfl_xor(mx, 2));
      mx = fmaxf(mx, __shfl_xor(mx, 4));
      mx = fmaxf(mx, __shfl_xor(mx, 8));
      float mn = fmaxf(mr[r], mx);
      float al = __expf(mr[r] - mn);
      p0[r] = __expf(s0[r] - mn);
      p1[r] = __expf(s1[r] - mn);
      float sm = p0[r] + p1[r];
      sm += __shfl_xor(sm, 1);
      sm += __shfl_xor(sm, 2);
      sm += __shfl_xor(sm, 4);
      sm += __shfl_xor(sm, 8);
      lr[r] = lr[r] * al + sm;
      mr[r] = mn;
      o[0][r] *= al; o[1][r] *= al; o[2][r] *= al; o[3][r] *= al;
    }

    __syncthreads();  // protect previous iter's P reads
#pragma unroll
    for (int r = 0; r < 4; r++) {
      P[wave][quad * 4 + r][l16] = f2bf(p0[r]);
      P[wave][quad * 4 + r][16 + l16] = f2bf(p1[r]);
    }
    __syncthreads();
    bf16x8 pf = ld_frag(&P[wave][l16][quad * 8]);
#pragma unroll
    for (int nt = 0; nt < 4; nt++) {
      bf16x8 vf = ld_frag(Vt + (long)(nt * 16 + l16) * 2048 + j0 + quad * 8);
      o[nt] = MFMA16(pf, vf, o[nt]);
    }
  }

  const int bI = bh >> 4, hh = bh & 15;
#pragma unroll
  for (int nt = 0; nt < 4; nt++) {
#pragma unroll
    for (int r = 0; r < 4; r++) {
      int l = qbase + quad * 4 + r;
      float v = o[nt][r] / lr[r];
      ctx[((long)(bI * 2048 + l)) * 1024 + hh * 64 + nt * 16 + l16] = f2bf(v);
    }
  }
}

// ---------------- residual + LayerNorm -------------------------------------
// out = LN(a+b)*g + be ; optional bf16 copy of out
__global__ __launch_bounds__(256) void ln_k(const float* __restrict__ a,
                                            const float* __restrict__ b,
                                            const float* __restrict__ g,
                                            const float* __restrict__ be,
                                            float* __restrict__ outF,
                                            u16* __restrict__ outB) {
  const int row = blockIdx.x, tid = threadIdx.x;
  const float* pa = a + (long)row * 1024;
  const float* pb = b + (long)row * 1024;
  float v[4], s = 0.f, sq = 0.f;
#pragma unroll
  for (int i = 0; i < 4; i++) {
    int c = i * 256 + tid;
    v[i] = pa[c] + pb[c];
    s += v[i];
    sq += v[i] * v[i];
  }
#pragma unroll
  for (int off = 1; off < 64; off <<= 1) {
    s += __shfl_xor(s, off);
    sq += __shfl_xor(sq, off);
  }
  __shared__ float red[10];
  int wave = tid >> 6, lane = tid & 63;
  if (lane == 0) { red[wave * 2] = s; red[wave * 2 + 1] = sq; }
  __syncthreads();
  if (tid == 0) {
    float S = red[0] + red[2] + red[4] + red[6];
    float Q = red[1] + red[3] + red[5] + red[7];
    float mu = S * (1.0f / 1024.0f);
    float var = Q * (1.0f / 1024.0f) - mu * mu;
    red[8] = mu;
    red[9] = rsqrtf(var + 1e-5f);
  }
  __syncthreads();
  float mu = red[8], rstd = red[9];
#pragma unroll
  for (int i = 0; i < 4; i++) {
    int c = i * 256 + tid;
    float o = (v[i] - mu) * rstd * g[c] + be[c];
    outF[(long)row * 1024 + c] = o;
    if (outB) outB[(long)row * 1024 + c] = f2bf(o);
  }
}

// ---------------------------------------------------------------------------
extern "C" void kernel_launch(void* const* d_in, const int* in_sizes, int n_in,
                              void* d_out, int out_size, void* d_ws, size_t ws_size,
                              hipStream_t stream) {
  const float* x  = (const float*)d_in[0];
  const float* Wq = (const float*)d_in[1];  const float* bq = (const float*)d_in[2];
  const float* Wk = (const float*)d_in[3];  const float* bk = (const float*)d_in[4];
  const float* Wv = (const float*)d_in[5];  const float* bv = (const float*)d_in[6];
  const float* Wo = (const float*)d_in[7];  const float* bo = (const float*)d_in[8];
  const float* W1 = (const float*)d_in[9];  const float* b1 = (const float*)d_in[10];
  const float* W2 = (const float*)d_in[11]; const float* b2 = (const float*)d_in[12];
  const float* g1 = (const float*)d_in[13]; const float* be1 = (const float*)d_in[14];
  const float* g2 = (const float*)d_in[15]; const float* be2 = (const float*)d_in[16];

  char* ws = (char*)d_ws;
  size_t off = 0;
  auto alloc = [&](size_t bytes) {
    size_t o = off;
    off += (bytes + 255) & ~(size_t)255;
    return o;
  };
  u16*   xb     = (u16*)(ws + alloc(4096UL * 1024 * 2));
  u16*   wqkvT  = (u16*)(ws + alloc(3072UL * 1024 * 2));
  u16*   woT    = (u16*)(ws + alloc(1024UL * 1024 * 2));
  u16*   w1T    = (u16*)(ws + alloc(4096UL * 1024 * 2));
  u16*   w2T    = (u16*)(ws + alloc(1024UL * 4096 * 2));
  u16*   qb     = (u16*)(ws + alloc(32UL * 2048 * 64 * 2));
  u16*   kb     = (u16*)(ws + alloc(32UL * 2048 * 64 * 2));
  u16*   vTb    = (u16*)(ws + alloc(32UL * 64 * 2048 * 2));
  u16*   ctx    = (u16*)(ws + alloc(4096UL * 1024 * 2));
  float* attnO  = (float*)(ws + alloc(4096UL * 1024 * 4));
  float* h      = (float*)(ws + alloc(4096UL * 1024 * 4));
  u16*   hb     = (u16*)(ws + alloc(4096UL * 1024 * 2));
  u16*   ff1    = (u16*)(ws + alloc(4096UL * 4096 * 2));
  float* ff2    = (float*)(ws + alloc(4096UL * 1024 * 4));
  if (off > ws_size) return;  // workspace too small: bail (bench will flag)

  // 1) bf16 conversions / weight transposes
  cvt_bf16_k<<<4096, 256, 0, stream>>>(x, xb);
  transpose_bf16_k<<<dim3(32, 32), 256, 0, stream>>>(Wq, wqkvT, 1024, 1024);
  transpose_bf16_k<<<dim3(32, 32), 256, 0, stream>>>(Wk, wqkvT + 1024 * 1024, 1024, 1024);
  transpose_bf16_k<<<dim3(32, 32), 256, 0, stream>>>(Wv, wqkvT + 2 * 1024 * 1024, 1024, 1024);
  transpose_bf16_k<<<dim3(32, 32), 256, 0, stream>>>(Wo, woT, 1024, 1024);
  transpose_bf16_k<<<dim3(128, 32), 256, 0, stream>>>(W1, w1T, 1024, 4096);
  transpose_bf16_k<<<dim3(32, 128), 256, 0, stream>>>(W2, w2T, 4096, 1024);

  // 2) QKV projection (N=3072 fused), scatter epilogue
  gemm_k<0><<<dim3(48, 64), 256, 0, stream>>>(xb, wqkvT, 4096, 3072, 1024,
                                              nullptr, nullptr, nullptr,
                                              qb, kb, vTb, bq, bk, bv);
  // 3) attention
  attn_k<<<dim3(32, 32), 256, 0, stream>>>(qb, kb, vTb, ctx);
  // 4) output projection
  gemm_k<1><<<dim3(16, 64), 256, 0, stream>>>(ctx, woT, 4096, 1024, 1024,
                                              bo, attnO, nullptr,
                                              nullptr, nullptr, nullptr, nullptr, nullptr, nullptr);
  // 5) residual + LN1 (fp32 h + bf16 hb)
  ln_k<<<4096, 256, 0, stream>>>(x, attnO, g1, be1, h, hb);
  // 6) FFN up + GELU
  gemm_k<2><<<dim3(64, 64), 256, 0, stream>>>(hb, w1T, 4096, 4096, 1024,
                                              b1, nullptr, ff1,
                                              nullptr, nullptr, nullptr, nullptr, nullptr, nullptr);
  // 7) FFN down
  gemm_k<1><<<dim3(16, 64), 256, 0, stream>>>(ff1, w2T, 4096, 1024, 4096,
                                              b2, ff2, nullptr,
                                              nullptr, nullptr, nullptr, nullptr, nullptr, nullptr);
  // 8) residual + LN2 -> out
  ln_k<<<4096, 256, 0, stream>>>(h, ff2, g2, be2, (float*)d_out, nullptr);
}